// Round 5
// baseline (151.312 us; speedup 1.0000x reference)
//
#include <hip/hip_runtime.h>

// Fused: out[i,j] = sum_d x[i,d] * Weff[j,d] + b[j]
// Weff[j,d] = W[j,d] + sum_k M[k,d] * W[j, 42+k]  (M = connect-4 window masks,
// incl. reference bugs: diag windows are full 4x4 blocks; feats 57..68 zero).
// Weff (308 floats) is recomputed per block under the x-staging load shadow.

#define ROW_PAD 43   // 42+1: stride 43 across lanes -> 2 lanes/bank = free

__global__ __launch_bounds__(256)
void ddqn_fused(const float* __restrict__ gs,
                const float* __restrict__ W,
                const float* __restrict__ b,
                float* __restrict__ out) {
    __shared__ float wl[7 * 44];             // Weff, rows padded to 44 (f4 align)
    __shared__ float bl[7];
    __shared__ float tile[4][64 * ROW_PAD];  // per-wave 64x43 x slabs
    __shared__ float obuf[4][64 * 7];        // per-wave output transpose buf

    const int t = threadIdx.x;
    const int w = t >> 6;
    const int l = t & 63;
    float* tw = tile[w];

    const size_t tileIdx = (size_t)blockIdx.x * 4 + w;   // 64 rows per wave
    const float* src = gs + tileIdx * (64 * 42);

    // ---- Stage x: f = k*64 + l. Global: 64 consecutive lanes -> 256B/instr,
    // perfectly coalesced. LDS: addresses consecutive (+1 at row crossings).
    {
        int row = l / 42;
        int col = l - row * 42;
        #pragma unroll
        for (int k = 0; k < 42; ++k) {
            tw[row * ROW_PAD + col] = src[k * 64 + l];
            row += 1; col += 22;             // advance f by 64 = 1*42 + 22
            if (col >= 42) { col -= 42; row += 1; }
        }
    }

    // ---- Weff recompute (hides under the staging loads' HBM latency).
    for (int i = t; i < 7 * 44; i += 256) {
        int j = i / 44, d = i - j * 44;
        float acc = 0.0f;
        if (d < 42) {
            acc = W[j * 111 + d];
            int r = d / 7, c = d - r * 7;
            const float* ws = W + j * 111 + 42;
            #pragma unroll
            for (int i4 = 0; i4 < 4; ++i4)          // 24 row windows
                if (c >= i4 && c <= i4 + 3) acc += ws[r * 4 + i4];
            #pragma unroll
            for (int i3 = 0; i3 < 3; ++i3)          // 21 col windows
                if (r >= i3 && r <= i3 + 3) acc += ws[24 + c * 3 + i3];
            #pragma unroll
            for (int off = 0; off < 3; ++off)       // 12 "diag" (full 4x4 bug)
                #pragma unroll
                for (int col4 = 0; col4 < 4; ++col4)
                    if (r >= 2 - off && r <= 5 - off && c >= col4 && c <= col4 + 3)
                        acc += ws[45 + off * 4 + col4];
        }
        wl[i] = acc;                                // feats 57..68: zero masks
    }
    if (t < 7) bl[t] = b[t];
    __syncthreads();   // wl/bl ready (also drains the per-wave x staging)

    // ---- Compute: one row per thread. x scalar LDS reads (stride 43 across
    // lanes = free); weights via wave-uniform float4 broadcasts.
    float acc[7];
    #pragma unroll
    for (int j = 0; j < 7; ++j) acc[j] = bl[j];

    const float* xrow = tw + l * ROW_PAD;
    const float4* wl4 = (const float4*)wl;
    #pragma unroll
    for (int dq = 0; dq < 44; dq += 4) {
        float x0 = xrow[dq];
        float x1 = xrow[dq + 1];
        float x2 = (dq + 2 < 42) ? xrow[dq + 2] : 0.0f;
        float x3 = (dq + 3 < 42) ? xrow[dq + 3] : 0.0f;
        #pragma unroll
        for (int j = 0; j < 7; ++j) {
            const float4 wv = wl4[j * 11 + (dq >> 2)];
            acc[j] = fmaf(x0, wv.x, acc[j]);
            acc[j] = fmaf(x1, wv.y, acc[j]);
            acc[j] = fmaf(x2, wv.z, acc[j]);
            acc[j] = fmaf(x3, wv.w, acc[j]);
        }
    }

    // ---- Coalesced stores via per-wave LDS transpose.
    // Write: addr = l*7+j, stride 7 across lanes, gcd(7,32)=1 -> 2 lanes/bank.
    float* ob = obuf[w];
    #pragma unroll
    for (int j = 0; j < 7; ++j) ob[l * 7 + j] = acc[j];
    __builtin_amdgcn_wave_barrier();   // intra-wave DS in-order; fence compiler
    // Read back linear, store 1792B contiguous per wave: 7 x 256B coalesced.
    float* o = out + tileIdx * 448;
    #pragma unroll
    for (int k = 0; k < 7; ++k) o[k * 64 + l] = ob[k * 64 + l];
}

extern "C" void kernel_launch(void* const* d_in, const int* in_sizes, int n_in,
                              void* d_out, int out_size, void* d_ws, size_t ws_size,
                              hipStream_t stream) {
    const float* gs = (const float*)d_in[0];   // [B, 42] f32
    const float* W  = (const float*)d_in[1];   // [7, 111] f32
    const float* b  = (const float*)d_in[2];   // [7] f32
    float* out = (float*)d_out;                // [B, 7] f32

    int B = in_sizes[0] / 42;                  // 524288
    int tiles = B / 64;                        // 8192 wave-tiles
    ddqn_fused<<<dim3(tiles / 4), dim3(256), 0, stream>>>(gs, W, b, out);
}

// Round 7
// 149.501 us; speedup vs baseline: 1.0121x; 1.0121x over previous
//
#include <hip/hip_runtime.h>

// Fused: out[i,j] = sum_d x[i,d] * Weff[j,d] + b[j]
// Weff[j,d] = W[j,d] + sum_k M[k,d] * W[j, 42+k]  (M = connect-4 window masks,
// incl. reference bugs: diag windows are full 4x4 blocks; feats 57..68 zero).
//
// R6 mechanism under test: async global->LDS staging (global_load_lds) so all
// 12 staging instructions per wave are in flight at once (previous rounds'
// load->ds_write interleave serialized on vmcnt waits -> ~2.4 TB/s ceiling).

#define TILE_F 2688   // 64 rows * 42 floats, LINEAR per-wave LDS tile
                      // (global_load_lds scatters lane*size from a uniform
                      //  base -> layout must be linear; pad would break it)

__global__ __launch_bounds__(256)
void ddqn_fused(const float* __restrict__ gs,
                const float* __restrict__ W,
                const float* __restrict__ b,
                float* __restrict__ out) {
    __shared__ __align__(16) float wl[7 * 44];      // Weff, rows padded to 44
    __shared__ __align__(16) float tile[4][TILE_F]; // per-wave 64x42 x slabs

    const int t = threadIdx.x;
    const int w = t >> 6;
    const int l = t & 63;
    float* tw = tile[w];

    const size_t tileIdx = (size_t)blockIdx.x * 4 + w;   // 64 rows per wave
    const float* src = gs + tileIdx * TILE_F;

    // ---- Async stage: 10 x b128 (1 KB/instr) + 2 x b32, direct to LDS.
    // Global addr is per-lane (16B apart, perfectly coalesced); LDS dest is
    // wave-uniform base, HW writes lane l at base + l*width. No VGPR round
    // trip, no waitcnt until the barrier -> all loads simultaneously live.
    #pragma unroll
    for (int k = 0; k < 10; ++k) {
        __builtin_amdgcn_global_load_lds(
            (const __attribute__((address_space(1))) void*)(src + k * 256 + l * 4),
            (__attribute__((address_space(3))) void*)(tw + k * 256),
            16, 0, 0);
    }
    #pragma unroll
    for (int m = 0; m < 2; ++m) {
        __builtin_amdgcn_global_load_lds(
            (const __attribute__((address_space(1))) void*)(src + 2560 + m * 64 + l),
            (__attribute__((address_space(3))) void*)(tw + 2560 + m * 64),
            4, 0, 0);
    }

    // ---- Weff recompute (runs while the staging loads are in flight).
    for (int i = t; i < 7 * 44; i += 256) {
        int j = i / 44, d = i - j * 44;
        float acc = 0.0f;
        if (d < 42) {
            acc = W[j * 111 + d];
            int r = d / 7, c = d - r * 7;
            const float* ws = W + j * 111 + 42;
            #pragma unroll
            for (int i4 = 0; i4 < 4; ++i4)          // 24 row windows
                if (c >= i4 && c <= i4 + 3) acc += ws[r * 4 + i4];
            #pragma unroll
            for (int i3 = 0; i3 < 3; ++i3)          // 21 col windows
                if (r >= i3 && r <= i3 + 3) acc += ws[24 + c * 3 + i3];
            #pragma unroll
            for (int off = 0; off < 3; ++off)       // 12 "diag" (full 4x4 bug)
                #pragma unroll
                for (int c4 = 0; c4 < 4; ++c4)
                    if (r >= 2 - off && r <= 5 - off && c >= c4 && c <= c4 + 3)
                        acc += ws[45 + off * 4 + c4];
        }
        wl[i] = acc;                                // feats 57..68: zero masks
    }
    __syncthreads();   // drains vmcnt(0): staged x AND wl both ready

    // ---- Compute: one row per thread. x scalar LDS reads (lane stride 42:
    // 4 lanes/bank = 1.58x, negligible); weights via wave-uniform float4
    // broadcasts (conflict-free).
    float x[44];
    const float* xr = tw + l * 42;
    #pragma unroll
    for (int d = 0; d < 42; ++d) x[d] = xr[d];
    x[42] = x[43] = 0.0f;

    float acc[7];
    #pragma unroll
    for (int j = 0; j < 7; ++j) acc[j] = b[j];      // uniform -> s_load

    const float4* wl4 = (const float4*)wl;
    #pragma unroll
    for (int dq = 0; dq < 11; ++dq) {
        #pragma unroll
        for (int j = 0; j < 7; ++j) {
            const float4 wv = wl4[j * 11 + dq];
            acc[j] = fmaf(x[dq * 4 + 0], wv.x, acc[j]);
            acc[j] = fmaf(x[dq * 4 + 1], wv.y, acc[j]);
            acc[j] = fmaf(x[dq * 4 + 2], wv.z, acc[j]);
            acc[j] = fmaf(x[dq * 4 + 3], wv.w, acc[j]);
        }
    }

    // ---- Direct stores (R2-style; WRITE_SIZE was exact, store path fine).
    float* o = out + (tileIdx * 64 + l) * 7;
    #pragma unroll
    for (int j = 0; j < 7; ++j) o[j] = acc[j];
}

extern "C" void kernel_launch(void* const* d_in, const int* in_sizes, int n_in,
                              void* d_out, int out_size, void* d_ws, size_t ws_size,
                              hipStream_t stream) {
    const float* gs = (const float*)d_in[0];   // [B, 42] f32
    const float* W  = (const float*)d_in[1];   // [7, 111] f32
    const float* b  = (const float*)d_in[2];   // [7] f32
    float* out = (float*)d_out;                // [B, 7] f32

    int B = in_sizes[0] / 42;                  // 524288
    int tiles = B / 64;                        // 8192 wave-tiles
    ddqn_fused<<<dim3(tiles / 4), dim3(256), 0, stream>>>(gs, W, b, out);
}